// Round 11
// baseline (136.212 us; speedup 1.0000x reference)
//
#include <hip/hip_runtime.h>

#define N_NODES 50000
#define N_EDGES 1200000
#define N_TILES (N_NODES / 16)   // 3125, exact
#define W1T_STRIDE 72            // bf16 elems per j-row in LDS (16B aligned)
#define K1_BLOCKS 782            // 3128 waves >= 3125 tiles, one-shot

#define N_BUCKETS 196            // ceil(50000/256) row buckets of 256 nodes
#define BUCKET_CAP 7168          // mean 6122, sigma ~78 -> 13 sigma headroom
#define EDGES_PER_BLOCK 1920     // binning block size (R8-proven LDS use)
#define KA_BLOCKS 625            // 1.2M / 1920 exact
#define D1_BLOCKS (K1_BLOCKS + KA_BLOCKS)   // 1407: precompute + bin fused
#define KB_SPLIT 4               // segments per bucket in the MLP kernel

typedef __attribute__((ext_vector_type(8))) short short8;   // 8 bf16
typedef __attribute__((ext_vector_type(4))) float floatx4;  // MFMA acc

__device__ __forceinline__ unsigned short f32_to_bf16(float f) {
    unsigned int v = __float_as_uint(f);
    unsigned int r = v + 0x7FFFu + ((v >> 16) & 1u);
    return (unsigned short)(r >> 16);
}
__device__ __forceinline__ float bf16_to_f32(unsigned short s) {
    return __uint_as_float(((unsigned int)s) << 16);
}
__device__ __forceinline__ unsigned int pack_bf16x2(float lo, float hi) {
    return (unsigned int)f32_to_bf16(lo) | ((unsigned int)f32_to_bf16(hi) << 16);
}

// ---------------------------------------------------------------------------
// Dispatch 1 (fused): blocks [0, K1_BLOCKS) do layer-1 precompute (MFMA GEMM,
// R4-proven) + zero `out`; blocks [K1_BLOCKS, D1_BLOCKS) bin edge IDs by row
// bucket. NEW: row values cached in LDS (u16) during the rank pass so the
// store pass never re-reads `row` from global.
// P1 (row-halves) / P2 (col-halves): 32 bf16 per node, 3.2 MB each (P2 is
// L2-resident in KB). Position p = 2n+g holds feature (n + 16g); KB loads W2
// fragments with the matching permutation F(q,i) = 4q + (i>>1) + 16(i&1).
// Bin entry u32 = (row & 255) << 24 | col.
// ---------------------------------------------------------------------------
__global__ __launch_bounds__(256) void fused_pre_bin(
    const float* __restrict__ x, const float* __restrict__ W1,
    const float* __restrict__ b1,
    const int* __restrict__ row, const int* __restrict__ col,
    unsigned short* __restrict__ P1, unsigned short* __restrict__ P2,
    unsigned int* __restrict__ buf, int* __restrict__ cursor,
    float* __restrict__ out)
{
    __shared__ union {
        unsigned short W1t[64 * W1T_STRIDE];                // 9216 B
        struct {
            unsigned short rankv[EDGES_PER_BLOCK];          // 3840 B
            unsigned short rowv[EDGES_PER_BLOCK];           // 3840 B (r<65536)
            int hist[N_BUCKETS];                            //  784 B
            int base[N_BUCKETS];                            //  784 B
        } bin;                                              // 9248 B total
    } sh;

    const int tid = threadIdx.x;
    const int bid = blockIdx.x;

    if (bid < K1_BLOCKS) {
        // ================= precompute path =================
        const int gtid = bid * 256 + tid;
        for (int i = gtid; i < N_NODES; i += K1_BLOCKS * 256)
            out[i] = 0.0f;   // KB atomically accumulates into out

        for (int e = tid; e < 128 * 32; e += 256) {
            const int kp = e >> 5, jp = e & 31;
            sh.W1t[((kp < 64) ? jp : jp + 32) * W1T_STRIDE + (kp & 63)] =
                f32_to_bf16(W1[e]);
        }
        __syncthreads();

        const int lane = tid & 63;
        const int n = lane & 15;
        const int q = lane >> 4;

        const int tile = bid * 4 + (tid >> 6);
        if (tile >= N_TILES) return;

        short8 bw[4][2];
        #pragma unroll
        for (int G = 0; G < 4; ++G)
            #pragma unroll
            for (int h = 0; h < 2; ++h)
                bw[G][h] = *(const short8*)
                    &sh.W1t[(n + 16 * G) * W1T_STRIDE + h * 32 + q * 8];
        const float bias0 = b1[n], bias1 = b1[n + 16];

        const int node = tile * 16 + n;
        const float4* xp  = (const float4*)(x + (size_t)node * 64 + q * 8);
        const float4 xa = xp[0], xb = xp[1];
        const float4* xp2 = (const float4*)(x + (size_t)node * 64 + 32 + q * 8);
        const float4 xc = xp2[0], xd = xp2[1];

        short8 a0, a1;
        a0[0] = (short)f32_to_bf16(xa.x); a0[1] = (short)f32_to_bf16(xa.y);
        a0[2] = (short)f32_to_bf16(xa.z); a0[3] = (short)f32_to_bf16(xa.w);
        a0[4] = (short)f32_to_bf16(xb.x); a0[5] = (short)f32_to_bf16(xb.y);
        a0[6] = (short)f32_to_bf16(xb.z); a0[7] = (short)f32_to_bf16(xb.w);
        a1[0] = (short)f32_to_bf16(xc.x); a1[1] = (short)f32_to_bf16(xc.y);
        a1[2] = (short)f32_to_bf16(xc.z); a1[3] = (short)f32_to_bf16(xc.w);
        a1[4] = (short)f32_to_bf16(xd.x); a1[5] = (short)f32_to_bf16(xd.y);
        a1[6] = (short)f32_to_bf16(xd.z); a1[7] = (short)f32_to_bf16(xd.w);

        floatx4 acc[4];
        #pragma unroll
        for (int G = 0; G < 4; ++G) {
            const float bi = (G == 0) ? bias0 : (G == 1) ? bias1 : 0.0f;
            acc[G] = (floatx4){bi, bi, bi, bi};
            acc[G] = __builtin_amdgcn_mfma_f32_16x16x32_bf16(a0, bw[G][0], acc[G], 0, 0, 0);
            acc[G] = __builtin_amdgcn_mfma_f32_16x16x32_bf16(a1, bw[G][1], acc[G], 0, 0, 0);
        }
        unsigned int* P1d = (unsigned int*)P1;
        unsigned int* P2d = (unsigned int*)P2;
        #pragma unroll
        for (int r = 0; r < 4; ++r) {
            const int nr = tile * 16 + q * 4 + r;
            P1d[(size_t)nr * 16 + n] = pack_bf16x2(acc[0][r], acc[1][r]);
            P2d[(size_t)nr * 16 + n] = pack_bf16x2(acc[2][r], acc[3][r]);
        }
    } else {
        // ================= binning path =================
        for (int b = tid; b < N_BUCKETS; b += 256) sh.bin.hist[b] = 0;
        __syncthreads();

        const int blockStart = (bid - K1_BLOCKS) * EDGES_PER_BLOCK;

        for (int i = tid; i < EDGES_PER_BLOCK; i += 256) {
            const int r = row[blockStart + i];
            sh.bin.rowv[i]  = (unsigned short)r;
            sh.bin.rankv[i] = (unsigned short)atomicAdd(&sh.bin.hist[r >> 8], 1);
        }
        __syncthreads();

        for (int b = tid; b < N_BUCKETS; b += 256)
            sh.bin.base[b] = atomicAdd(&cursor[b], sh.bin.hist[b]);
        __syncthreads();

        for (int i = tid; i < EDGES_PER_BLOCK; i += 256) {
            const int r = (int)sh.bin.rowv[i];
            const int c = col[blockStart + i];
            const int bin = r >> 8;
            buf[(size_t)bin * BUCKET_CAP + sh.bin.base[bin] + (int)sh.bin.rankv[i]] =
                ((unsigned int)(r & 255) << 24) | (unsigned int)c;
        }
    }
}

// ---------------------------------------------------------------------------
// Dispatch 2 (KB): per-bucket MLP (layers 2+3, MFMA) + LDS fp32 row reduce.
// 512-thread blocks, 4 segments/bucket, wave-slot = s*8+wave, chunk stride 32.
// NEW: software-pipelined entry loads — chunk k+1's bin entries (and owner
// u-gather operands) are fetched while chunk k's P gathers/compute are in
// flight, removing the entry-load latency from the per-iteration chain.
// Row gathers hit the 16 KB P1 bucket window; col gathers hit L2-resident P2.
// ---------------------------------------------------------------------------
__global__ __launch_bounds__(512) void bucket_mlp(
    const float* __restrict__ u,
    const float* __restrict__ W2, const float* __restrict__ b2,
    const float* __restrict__ W3, const float* __restrict__ b3,
    const unsigned short* __restrict__ P1, const unsigned short* __restrict__ P2,
    const unsigned int* __restrict__ buf, const int* __restrict__ cursor,
    float* __restrict__ out)
{
    __shared__ float accs[256];
    const int tid = threadIdx.x;
    if (tid < 256) accs[tid] = 0.0f;

    const int b = blockIdx.x >> 2;              // bucket
    const int s = blockIdx.x & (KB_SPLIT - 1);  // segment

    const int lane = tid & 63;
    const int n = lane & 15;
    const int q = lane >> 4;
    const int wave = tid >> 6;                  // 0..7

    // W2/W3 fragments with the P permutation F(q,i)
    short8 bf0, bf1;
    #pragma unroll
    for (int i = 0; i < 8; ++i) {
        const int F = q * 4 + (i >> 1) + 16 * (i & 1);
        bf0[i] = (short)f32_to_bf16(W2[F * 32 + n]);
        bf1[i] = (short)f32_to_bf16(W2[F * 32 + n + 16]);
    }
    const float w3n0 = W3[n], w3n1 = W3[n + 16];
    const float b2n0 = b2[n], b2n1 = b2[n + 16];
    const float bias3 = b3[0];

    __syncthreads();

    const int cnt = cursor[b];
    const unsigned int* bb = buf + (size_t)b * BUCKET_CAP;
    const unsigned short* P1b = P1 + (size_t)b * 256 * 32;  // bucket row window
    const int nch = (cnt + 31) >> 5;
    const int STRIDE = KB_SPLIT * 8;            // 32 wave-slots per bucket

    // ---- pipeline stage registers ----
    int ch = s * 8 + wave;
    int rl[2], cI[2];        // current chunk's gather-lane entries
    int r2 = 0; float u2 = 0.0f;                 // current owner-lane data

    if (ch < nch) {
        const int base0 = ch * 32;
        #pragma unroll
        for (int t = 0; t < 2; ++t) {
            int e = base0 + t * 16 + n;
            if (e >= cnt) e = cnt - 1;
            const unsigned int ent = bb[e];
            rl[t] = (int)(ent >> 24);
            cI[t] = (int)(ent & 0x1FFFFu);
        }
        if (n < 8) {
            const int eloc = base0 + 16 * (n >> 2) + 4 * q + (n & 3);
            const unsigned int ent2 = bb[(eloc < cnt) ? eloc : 0];
            r2 = (int)(ent2 >> 24);
            u2 = (eloc < cnt) ? u[ent2 & 0x1FFFFu] : 0.0f;
        }
    }

    #pragma unroll 1
    while (ch < nch) {
        // ---- issue current chunk's P gathers immediately ----
        short8 v1[2], v2[2];
        #pragma unroll
        for (int t = 0; t < 2; ++t) {
            v1[t] = *(const short8*)(P1b + (size_t)rl[t] * 32 + q * 8);
            v2[t] = *(const short8*)(P2 + (size_t)cI[t] * 32 + q * 8);
        }

        // ---- prefetch next chunk's entries while gathers are in flight ----
        const int chn = ch + STRIDE;
        int nrl[2], ncI[2];
        int nr2 = 0; float nu2 = 0.0f;
        if (chn < nch) {
            const int base1 = chn * 32;
            #pragma unroll
            for (int t = 0; t < 2; ++t) {
                int e = base1 + t * 16 + n;
                if (e >= cnt) e = cnt - 1;
                const unsigned int ent = bb[e];
                nrl[t] = (int)(ent >> 24);
                ncI[t] = (int)(ent & 0x1FFFFu);
            }
            if (n < 8) {
                const int eloc = base1 + 16 * (n >> 2) + 4 * q + (n & 3);
                const unsigned int ent2 = bb[(eloc < cnt) ? eloc : 0];
                nr2 = (int)(ent2 >> 24);
                nu2 = (eloc < cnt) ? u[ent2 & 0x1FFFFu] : 0.0f;
            }
        }

        // ---- layers 2+3 (R4-proven core) ----
        float tr[2][4];
        #pragma unroll
        for (int t = 0; t < 2; ++t) {
            short8 a;
            #pragma unroll
            for (int i = 0; i < 8; ++i) {
                const float f1 = bf16_to_f32((unsigned short)v1[t][i]);
                const float f2 = bf16_to_f32((unsigned short)v2[t][i]);
                a[i] = (short)f32_to_bf16(fmaxf(f1 + f2, 0.0f));
            }
            floatx4 d0 = {b2n0, b2n0, b2n0, b2n0};
            floatx4 d1 = {b2n1, b2n1, b2n1, b2n1};
            d0 = __builtin_amdgcn_mfma_f32_16x16x32_bf16(a, bf0, d0, 0, 0, 0);
            d1 = __builtin_amdgcn_mfma_f32_16x16x32_bf16(a, bf1, d1, 0, 0, 0);
            #pragma unroll
            for (int r = 0; r < 4; ++r)
                tr[t][r] = fmaxf(d0[r], 0.0f) * w3n0 + fmaxf(d1[r], 0.0f) * w3n1;
        }

        #pragma unroll
        for (int mask = 1; mask < 16; mask <<= 1) {
            #pragma unroll
            for (int t = 0; t < 2; ++t)
                #pragma unroll
                for (int r = 0; r < 4; ++r)
                    tr[t][r] += __shfl_xor(tr[t][r], mask, 64);
        }

        if (n < 8) {
            const float va0 = (n & 4) ? tr[1][0] : tr[0][0];
            const float va1 = (n & 4) ? tr[1][1] : tr[0][1];
            const float va2 = (n & 4) ? tr[1][2] : tr[0][2];
            const float va3 = (n & 4) ? tr[1][3] : tr[0][3];
            const float vb0 = (n & 2) ? va2 : va0;
            const float vb1 = (n & 2) ? va3 : va1;
            const float v   = (n & 1) ? vb1 : vb0;
            atomicAdd(&accs[r2], (v + bias3) * u2);
        }

        // ---- rotate pipeline ----
        rl[0] = nrl[0]; rl[1] = nrl[1];
        cI[0] = ncI[0]; cI[1] = ncI[1];
        r2 = nr2; u2 = nu2;
        ch = chn;
    }

    __syncthreads();

    if (tid < 256) {
        const int node = b * 256 + tid;
        if (node < N_NODES) atomicAdd(out + node, accs[tid]);
    }
}

extern "C" void kernel_launch(void* const* d_in, const int* in_sizes, int n_in,
                              void* d_out, int out_size, void* d_ws, size_t ws_size,
                              hipStream_t stream)
{
    const float* x    = (const float*)d_in[0];
    const int*   eidx = (const int*)  d_in[1];   // [2, E] int32
    const float* u    = (const float*)d_in[2];
    const float* W1   = (const float*)d_in[3];
    const float* b1   = (const float*)d_in[4];
    const float* W2   = (const float*)d_in[5];
    const float* b2   = (const float*)d_in[6];
    const float* W3   = (const float*)d_in[7];
    const float* b3   = (const float*)d_in[8];

    const int* row = eidx;
    const int* col = eidx + N_EDGES;

    // ws layout: P1 3.2MB | P2 3.2MB | buf 5.62MB | cursor 784B
    unsigned short* P1 = (unsigned short*)d_ws;
    unsigned short* P2 = (unsigned short*)((char*)d_ws + (size_t)N_NODES * 64);
    unsigned int*  buf = (unsigned int*)((char*)d_ws + (size_t)N_NODES * 128);
    int* cursor = (int*)((char*)d_ws + (size_t)N_NODES * 128
                         + (size_t)N_BUCKETS * BUCKET_CAP * 4);
    float* out = (float*)d_out;

    // zero bucket cursors (784 B, must precede the binning blocks of D1)
    hipMemsetAsync(cursor, 0, N_BUCKETS * sizeof(int), stream);

    // D1: precompute P1/P2 + zero out  ||  bin edge IDs (concurrent halves)
    fused_pre_bin<<<D1_BLOCKS, 256, 0, stream>>>(
        x, W1, b1, row, col, P1, P2, buf, cursor, out);

    // D2: per-bucket MLP + LDS reduce -> out (512-thread, pipelined)
    bucket_mlp<<<N_BUCKETS * KB_SPLIT, 512, 0, stream>>>(
        u, W2, b2, W3, b3, P1, P2, buf, cursor, out);
}